// Round 2
// baseline (56.191 us; speedup 1.0000x reference)
//
#include <hip/hip_runtime.h>

// ChamferLoss: preds (8,3,2048,8) f32, gts (8,3,2048) f32, idx (64,2) int.
// x[b][n][c] = preds[i0, c, n, m1]; y[b][n][c] = gts[i0, c, n]; i0=idx[b,0], m1=idx[b,1].
// loss = ( sum_j min_i ||x_i-y_j||^2 + sum_i min_j ||x_i-y_j||^2 ) / 64, summed over b.

#define NPTS 2048
#define NB 64
#define RCH 256                 // refs per chunk (== block size)
#define NRCH (NPTS / RCH)       // 8
#define QPT 8                   // queries per thread (256*8 == 2048)
#define BLK 256
#define NMIN (2 * NB * NPTS)    // 262144 min slots

#define PREDS_A 49152           // 3*2048*8
#define PREDS_C 16384           // 2048*8
#define GTS_A 6144              // 3*2048
#define GTS_C 2048

__global__ __launch_bounds__(256) void cf_init(unsigned* __restrict__ minbuf) {
    int i = blockIdx.x * 256 + threadIdx.x;
    minbuf[i] = 0x7F800000u;    // +inf
}

__global__ __launch_bounds__(BLK) void cf_min(
    const float* __restrict__ preds, const float* __restrict__ gts,
    const int* __restrict__ idx, unsigned* __restrict__ minbuf)
{
    const int tid = threadIdx.x;
    const int bid = blockIdx.x;            // [dir:1][b:6][rchunk:3]
    const int rchunk = bid & (NRCH - 1);
    const int b = (bid >> 3) & 63;
    const int dir = bid >> 9;              // 0: queries=x refs=y ; 1: queries=y refs=x

    const int i0 = idx[2 * b];
    const int m1 = idx[2 * b + 1];

    const float* pbase = preds + i0 * PREDS_A + m1;  // x[c][n] at pbase[n*8 + c*PREDS_C]
    const float* gbase = gts + i0 * GTS_A;           // y[c][n] at gbase[n + c*GTS_C]

    // ---- stage this block's ref chunk into LDS as (r0,r1,r2, r0^2+r1^2+r2^2) ----
    __shared__ float4 sref[RCH];
    {
        const int jj = rchunk * RCH + tid;
        float r0, r1, r2;
        if (dir == 0) {
            r0 = gbase[jj];
            r1 = gbase[jj + GTS_C];
            r2 = gbase[jj + 2 * GTS_C];
        } else {
            const float* pp = pbase + jj * 8;
            r0 = pp[0];
            r1 = pp[PREDS_C];
            r2 = pp[2 * PREDS_C];
        }
        const float rr = fmaf(r0, r0, fmaf(r1, r1, r2 * r2));
        sref[tid] = make_float4(r0, r1, r2, rr);
    }

    // ---- load this thread's 8 queries into registers (coords pre-scaled by -2) ----
    float nq0[QPT], nq1[QPT], nq2[QPT], rq[QPT], mn[QPT];
#pragma unroll
    for (int q = 0; q < QPT; ++q) {
        const int n = tid + BLK * q;
        float q0, q1, q2;
        if (dir == 0) {
            const float* pp = pbase + n * 8;
            q0 = pp[0]; q1 = pp[PREDS_C]; q2 = pp[2 * PREDS_C];
        } else {
            q0 = gbase[n]; q1 = gbase[n + GTS_C]; q2 = gbase[n + 2 * GTS_C];
        }
        rq[q]  = fmaf(q0, q0, fmaf(q1, q1, q2 * q2));
        nq0[q] = -2.0f * q0;
        nq1[q] = -2.0f * q1;
        nq2[q] = -2.0f * q2;
        mn[q]  = INFINITY;
    }

    __syncthreads();

    // ---- main loop: per ref, 3 FMA + 1 min per query; min tracks (rr - 2*dot) ----
#pragma unroll 4
    for (int j = 0; j < RCH; ++j) {
        const float4 r = sref[j];
#pragma unroll
        for (int q = 0; q < QPT; ++q) {
            float t = fmaf(nq0[q], r.x, r.w);
            t = fmaf(nq1[q], r.y, t);
            t = fmaf(nq2[q], r.z, t);
            mn[q] = fminf(mn[q], t);
        }
    }

    // ---- combine chunk partial mins: nonneg floats are uint-order-preserving ----
    unsigned* mb = minbuf + (dir * NB + b) * NPTS;
#pragma unroll
    for (int q = 0; q < QPT; ++q) {
        const int n = tid + BLK * q;
        const float d = fmaxf(rq[q] + mn[q], 0.0f);
        atomicMin(mb + n, __float_as_uint(d));
    }
}

__global__ __launch_bounds__(256) void cf_reduce1(const unsigned* __restrict__ minbuf,
                                                  float* __restrict__ partial) {
    __shared__ float sm[4];
    const int base = blockIdx.x * 1024;
    float s = 0.0f;
    for (int k = threadIdx.x; k < 1024; k += 256)
        s += __uint_as_float(minbuf[base + k]);
#pragma unroll
    for (int off = 32; off > 0; off >>= 1)
        s += __shfl_down(s, off, 64);
    if ((threadIdx.x & 63) == 0) sm[threadIdx.x >> 6] = s;
    __syncthreads();
    if (threadIdx.x == 0)
        partial[blockIdx.x] = sm[0] + sm[1] + sm[2] + sm[3];
}

__global__ __launch_bounds__(256) void cf_reduce2(const float* __restrict__ partial,
                                                  float* __restrict__ out) {
    __shared__ float sm[4];
    float s = partial[threadIdx.x];
#pragma unroll
    for (int off = 32; off > 0; off >>= 1)
        s += __shfl_down(s, off, 64);
    if ((threadIdx.x & 63) == 0) sm[threadIdx.x >> 6] = s;
    __syncthreads();
    if (threadIdx.x == 0)
        out[0] = (sm[0] + sm[1] + sm[2] + sm[3]) * (1.0f / 64.0f);
}

extern "C" void kernel_launch(void* const* d_in, const int* in_sizes, int n_in,
                              void* d_out, int out_size, void* d_ws, size_t ws_size,
                              hipStream_t stream) {
    const float* preds = (const float*)d_in[0];
    const float* gts   = (const float*)d_in[1];
    const int*   idx   = (const int*)d_in[2];
    float* out = (float*)d_out;

    unsigned* minbuf = (unsigned*)d_ws;                                   // 1 MiB
    float* partial   = (float*)((char*)d_ws + NMIN * sizeof(unsigned));   // 1 KiB

    cf_init<<<NMIN / 256, 256, 0, stream>>>(minbuf);
    cf_min<<<2 * NB * NRCH, BLK, 0, stream>>>(preds, gts, idx, minbuf);
    cf_reduce1<<<NMIN / 1024, 256, 0, stream>>>(minbuf, partial);
    cf_reduce2<<<1, 256, 0, stream>>>(partial, out);
}